// Round 4
// baseline (199.855 us; speedup 1.0000x reference)
//
#include <hip/hip_runtime.h>
#include <math.h>

#define NPATH 1536
#define NSEG  65
#define NB    160
#define NA    160
#define CW    40   // chunks (waves) per (z,a)
#define PPW   4    // pairs per wave = NB/CW

// Piecewise-linear radial-MLP table: R[p](r) = r*slope + icpt, per-block
// Wigner/norm constants pre-folded. float4-packed, per segment 768 float4:
//   [  0..255]: (v*16+u) -> {A_s, A_i, B_s, B_i}   (l0-lane slots 0,1)
//   [256..511]: (v*16+u) -> {C_s, C_i, D_s, D_i}   (l1-lane slots 0,1)
//   [512..767]: (v*16+u) -> {E_s, E_i, F_s, F_i}   (l1-lane slots 2,3)
__device__ float  dg_thr[64];    // per-channel threshold -b1/W1 (inf if W1==0)
__device__ float4 dg_tbl4[NSEG * 768];

// One kernel does everything before k_main:
//  blocks 0..389  : table, one thread per (segment, path). Each block
//                   redundantly rank-sorts the 64 thresholds (trivial) and
//                   computes its segment's masked sums directly — 1560 waves
//                   in flight vs R3's 24.
//  blocks 390..469: zero d_out (2*160*64 = 80*256).
__global__ __launch_bounds__(256) void k_prep(const float* __restrict__ W1,
                                              const float* __restrict__ b1,
                                              const float* __restrict__ W2,
                                              const float* __restrict__ b2,
                                              float* __restrict__ out) {
    int bid = blockIdx.x, tid = threadIdx.x;
    if (bid >= 390) {
        out[(bid - 390) * 256 + tid] = 0.0f;
        return;
    }
    int tseg = bid / 6, tcol = bid % 6;
    __shared__ float tv[64], mw[64], mb[64];
    if (tid < 64) {
        float w = W1[tid], b = b1[tid];
        tv[tid] = (w != 0.0f) ? (-b / w) : __builtin_inff();
    }
    __syncthreads();
    if (tid < 64) {
        float mine = tv[tid];
        int rank = 0;
        for (int j = 0; j < 64; ++j) {
            float o = tv[j];
            rank += (o < mine || (o == mine && j < tid)) ? 1 : 0;
        }
        float w = W1[tid], b = b1[tid];
        // channel active at segment s (= #thresholds < r):
        //   w>0: r>t_c  <=> rank < s ; w<0: r<t_c <=> rank >= s ; w==0: b>0
        bool act = (w > 0.0f) ? (rank < tseg)
                 : (w < 0.0f) ? (rank >= tseg)
                              : (b > 0.0f);
        mw[tid] = act ? w : 0.0f;
        mb[tid] = act ? b : 0.0f;
        if (bid == 0) dg_thr[tid] = mine;
    }
    __syncthreads();

    int p = tcol * 256 + tid;
    int idx, half; float scl;
    if (p < 768) {
        int u = (p >> 4) & 15, v = p & 15;
        if (p < 256)      { idx = v * 16 + u;       half = 0; scl = 0.17677669529663687f; } // A
        else if (p < 512) { idx = v * 16 + u;       half = 1; scl = 0.6266570686577502f;  } // B
        else              { idx = 256 + v * 16 + u; half = 0; scl = 0.2558286876965162f;  } // C
    } else {
        int m = (p - 768) / 3, kk = (p - 768) % 3;
        int u = m >> 4, v = m & 15;
        if (kk == 0)      { idx = 256 + v * 16 + u; half = 1; scl = 0.125f;               } // D
        else if (kk == 1) { idx = 512 + v * 16 + u; half = 0; scl = 0.3133285343288751f;  } // E
        else              { idx = 512 + v * 16 + u; half = 1; scl = 0.7674950309598664f;  } // F
    }

    float A = 0.0f, B = 0.0f;
    #pragma unroll 8
    for (int c = 0; c < 64; ++c) {
        float w2 = W2[c * NPATH + p];   // coalesced across tid; W2 is L2-hot
        A = fmaf(mw[c], w2, A);
        B = fmaf(mb[c], w2, B);
    }
    float2* dst = (float2*)dg_tbl4;
    dst[tseg * 1536 + idx * 2 + half] = make_float2(scl * A, scl * (B + b2[p]));
}

__global__ __launch_bounds__(256, 4) void k_main(const float* __restrict__ feat,
                                                 const float* __restrict__ geom,
                                                 const float* __restrict__ mask,
                                                 float* __restrict__ out) {
    int wv   = threadIdx.x >> 6;
    int lane = threadIdx.x & 63;
    int gw   = blockIdx.x * 4 + wv;     // 4 waves of a block share za (40 % 4 == 0)
    int chunk = gw % CW;
    int za    = gw / CW;                // z*160 + a
    int z     = za / NA;

    __shared__ __align__(16) float sFeat[4][PPW][80]; // [0..15]=l0, [16..79]=f4-packed l1
    __shared__ float sAcc[4][64];

    const bool is0 = lane < 16;
    int u  = is0 ? lane : ((lane - 16) / 3);
    int i3 = is0 ? 0 : ((lane - 16) % 3);
    int waddr = is0 ? lane : (16 + u * 4 + i3);

    int o_base = (is0 ? 0 : 256) + u;   // first float4 slot within segment row
    float zfl  = is0 ? 1.4142135623730951f : 2.0f;  // zero-radius norm ratio
    float bx = (!is0 && i3 == 0) ? 1.0f : 0.0f;
    float by = (!is0 && i3 == 1) ? 1.0f : 0.0f;
    float bz = (!is0 && i3 == 2) ? 1.0f : 0.0f;

    float thrv = dg_thr[lane];

    const float is30 = 0.18257418583505536f;  // 1/sqrt(30)
    const float is10 = 0.31622776601683794f;  // 1/sqrt(10)
    const float c1sh = 0.4886025119029199f;
    const float c21 = 1.0925484305920792f, c22 = 0.31539156525252005f, c23 = 0.5462742152960396f;

    // ---- stage all PPW feature rows (wave-private LDS, no barrier) ----
    int b0 = chunk * PPW;
    #pragma unroll
    for (int it = 0; it < PPW; ++it) {
        float fv = feat[((size_t)(z * NB + b0 + it)) * 64 + lane];
        sFeat[wv][it][waddr] = fv;
    }

    // ---- precompute geometry/segment for all PPW pairs ----
    float rr[PPW], nxa[PPW], nya[PPW], nza[PPW], zfa[PPW];
    int rowo[PPW];
    #pragma unroll
    for (int it = 0; it < PPW; ++it) {
        const float* g = geom + ((size_t)za * NB + b0 + it) * 3;
        float gx = g[0], gy = g[1], gz = g[2];
        float r = sqrtf(gx * gx + gy * gy + gz * gz);
        bool zr = (r == 0.0f);
        float inv = zr ? 1.0f : (1.0f / r);
        nxa[it] = gx * inv; nya[it] = gy * inv; nza[it] = gz * inv;
        rr[it] = r;
        zfa[it] = zr ? zfl : 1.0f;
        unsigned long long bm = __ballot(thrv < r);
        rowo[it] = __popcll(bm) * 768;
    }

    float acc = 0.0f;

    #pragma unroll
    for (int it = 0; it < PPW; ++it) {
        float r = rr[it];
        float nx = nxa[it], ny = nya[it], nz = nza[it];

        // real SH (e3nn convention; l=1 order y,z,x)
        float Y1_0 = c1sh * ny, Y1_1 = c1sh * nz, Y1_2 = c1sh * nx;
        float Y2_0 = c21 * nx * ny;
        float Y2_1 = c21 * ny * nz;
        float Y2_2 = c22 * fmaf(3.0f, nz * nz, -1.0f);
        float Y2_3 = c21 * nx * nz;
        float Y2_4 = c23 * (nx * nx - ny * ny);

        // per-lane coefficient vectors (uniform inner loop):
        //  s += R0*(c0*f0) + R1*(d1.f1) + R2*(d2.f1) + R3*(d3.f1)
        float Yi = (i3 == 0) ? Y1_0 : (i3 == 1) ? Y1_1 : Y1_2;
        float c0 = is0 ? 1.0f : Yi;
        float d1x = is0 ? Y1_0 : bx;
        float d1y = is0 ? Y1_1 : by;
        float d1z = is0 ? Y1_2 : bz;
        float d2x = is0 ? 0.0f : ((i3 == 0) ? 0.0f   : (i3 == 1) ? -Y1_2 : Y1_1);
        float d2y = is0 ? 0.0f : ((i3 == 0) ? Y1_2   : (i3 == 1) ? 0.0f  : -Y1_0);
        float d2z = is0 ? 0.0f : ((i3 == 0) ? -Y1_1  : (i3 == 1) ? Y1_0  : 0.0f);
        float za_ = is10 * Y2_0, zb_ = is10 * Y2_1, zc_ = is10 * Y2_3;
        float zd_ = is30 * Y2_2, ze_ = is10 * Y2_4;
        float d3x = is0 ? 0.0f : ((i3 == 0) ? (-zd_ - ze_) : (i3 == 1) ? zb_ : za_);
        float d3y = is0 ? 0.0f : ((i3 == 0) ? zb_ : (i3 == 1) ? (2.0f * zd_) : zc_);
        float d3z = is0 ? 0.0f : ((i3 == 0) ? za_ : (i3 == 1) ? zc_ : (ze_ - zd_));

        const float4* __restrict__ row = dg_tbl4 + rowo[it];
        const float*  sp = &sFeat[wv][it][0];
        int o = o_base;
        // 4 independent accumulator chains (breaks the serial fma dependence)
        float s0 = 0.0f, s1 = 0.0f, s2 = 0.0f, s3 = 0.0f;
        #pragma unroll 8
        for (int v = 0; v < 16; ++v) {
            float4 t01 = row[o];
            float4 t23 = make_float4(0.0f, 0.0f, 0.0f, 0.0f);
            if (!is0) t23 = row[o + 256];     // exec-masked; l0 lanes keep zeros
            o += 16;
            float R0 = fmaf(r, t01.x, t01.y);
            float R1 = fmaf(r, t01.z, t01.w);
            float R2 = fmaf(r, t23.x, t23.y);
            float R3 = fmaf(r, t23.z, t23.w);
            float f0 = sp[v];                                 // LDS broadcast
            float4 fj = *(const float4*)&sp[16 + 4 * v];      // LDS broadcast (w unused)
            s0 = fmaf(R0, c0 * f0, s0);
            float dot1 = fmaf(d1z, fj.z, fmaf(d1y, fj.y, d1x * fj.x));
            s1 = fmaf(R1, dot1, s1);
            float dot2 = fmaf(d2z, fj.z, fmaf(d2y, fj.y, d2x * fj.x));
            s2 = fmaf(R2, dot2, s2);
            float dot3 = fmaf(d3z, fj.z, fmaf(d3y, fj.y, d3x * fj.x));
            s3 = fmaf(R3, dot3, s3);
        }
        acc = fmaf((s0 + s1) + (s2 + s3), zfa[it], acc);
    }

    sAcc[wv][lane] = acc;
    __syncthreads();
    if (threadIdx.x < 64) {
        float sum = sAcc[0][threadIdx.x] + sAcc[1][threadIdx.x]
                  + sAcc[2][threadIdx.x] + sAcc[3][threadIdx.x];
        sum *= mask[za];
        atomicAdd(&out[(size_t)za * 64 + threadIdx.x], sum);
    }
}

extern "C" void kernel_launch(void* const* d_in, const int* in_sizes, int n_in,
                              void* d_out, int out_size, void* d_ws, size_t ws_size,
                              hipStream_t stream) {
    (void)in_sizes; (void)n_in; (void)d_ws; (void)ws_size; (void)out_size;
    const float* feat = (const float*)d_in[0];
    const float* geom = (const float*)d_in[1];
    const float* mask = (const float*)d_in[2];
    const float* W1   = (const float*)d_in[3];
    const float* b1   = (const float*)d_in[4];
    const float* W2   = (const float*)d_in[5];
    const float* b2   = (const float*)d_in[6];
    float* out = (float*)d_out;

    k_prep<<<470, 256, 0, stream>>>(W1, b1, W2, b2, out);   // 390 table + 80 zero
    k_main<<<2 * NA * CW / 4, 256, 0, stream>>>(feat, geom, mask, out);
}

// Round 5
// 129.718 us; speedup vs baseline: 1.5407x; 1.5407x over previous
//
#include <hip/hip_runtime.h>
#include <math.h>

#define NPATH 1536
#define NSEG  65
#define NB    160
#define NA    160
#define CW    32   // chunks (waves) per (z,a)
#define PPW   5    // pairs per wave = NB/CW

// Piecewise-linear radial-MLP table: R(r) = r*slope + icpt, per-block
// Wigner/norm constants pre-folded. Interleaved so each lane's two float4
// loads per v are ADJACENT (one address, offset:0 / offset:16):
//   per segment: 1024 float4 (16 KB)
//   l0 region  [0..511]:   (v*16+u)*2     -> {A_s,A_i,B_s,B_i}, +1 -> zeros (pad)
//   l1 region  [512..1023]: 512+(v*16+u)*2 -> {C_s,C_i,D_s,D_i}, +1 -> {E_s,E_i,F_s,F_i}
__device__ float  dg_thr[64];    // per-channel threshold -b1/W1 (inf if W1==0)
__device__ float4 dg_tbl4[NSEG * 1024];

// blocks 0..389: table (one thread per (segment,path), direct masked sums —
// activity is a pure rank predicate, rank-sort recomputed per block).
// blocks 390..469: zero d_out.
__global__ __launch_bounds__(256) void k_prep(const float* __restrict__ W1,
                                              const float* __restrict__ b1,
                                              const float* __restrict__ W2,
                                              const float* __restrict__ b2,
                                              float* __restrict__ out) {
    int bid = blockIdx.x, tid = threadIdx.x;
    if (bid >= 390) {
        out[(bid - 390) * 256 + tid] = 0.0f;
        return;
    }
    int tseg = bid / 6, tcol = bid % 6;
    __shared__ float tv[64], mw[64], mb[64];
    if (tid < 64) {
        float w = W1[tid], b = b1[tid];
        tv[tid] = (w != 0.0f) ? (-b / w) : __builtin_inff();
    }
    __syncthreads();
    if (tid < 64) {
        float mine = tv[tid];
        int rank = 0;
        for (int j = 0; j < 64; ++j) {
            float o = tv[j];
            rank += (o < mine || (o == mine && j < tid)) ? 1 : 0;
        }
        float w = W1[tid], b = b1[tid];
        // active at segment s (= #thresholds < r):
        //   w>0: rank < s ; w<0: rank >= s ; w==0: b>0
        bool act = (w > 0.0f) ? (rank < tseg)
                 : (w < 0.0f) ? (rank >= tseg)
                              : (b > 0.0f);
        mw[tid] = act ? w : 0.0f;
        mb[tid] = act ? b : 0.0f;
        if (bid == 0) dg_thr[tid] = mine;
    }
    __syncthreads();

    int p = tcol * 256 + tid;
    int f2i; float scl;             // float2 index within the 2048-f2 segment row
    bool wpad = false; int padf4 = 0;
    if (p < 768) {
        int u = (p >> 4) & 15, v = p & 15;
        int e = (v * 16 + u) * 2;
        if (p < 256)      { f2i = e * 2 + 0;           scl = 0.17677669529663687f;  // A
                            wpad = true; padf4 = e + 1; }
        else if (p < 512) { f2i = e * 2 + 1;           scl = 0.6266570686577502f; } // B
        else              { f2i = (512 + e) * 2 + 0;   scl = 0.2558286876965162f; } // C
    } else {
        int m = (p - 768) / 3, kk = (p - 768) % 3;
        int u = m >> 4, v = m & 15;
        int e = 512 + (v * 16 + u) * 2;
        if (kk == 0)      { f2i = e * 2 + 1;       scl = 0.125f;              }  // D
        else if (kk == 1) { f2i = (e + 1) * 2 + 0; scl = 0.3133285343288751f; }  // E
        else              { f2i = (e + 1) * 2 + 1; scl = 0.7674950309598664f; }  // F
    }

    float A = 0.0f, B = 0.0f;
    #pragma unroll 8
    for (int c = 0; c < 64; ++c) {
        float w2 = W2[c * NPATH + p];   // coalesced across tid; W2 is L2-hot
        A = fmaf(mw[c], w2, A);
        B = fmaf(mb[c], w2, B);
    }
    float2* dst = (float2*)dg_tbl4;
    dst[tseg * 2048 + f2i] = make_float2(scl * A, scl * (B + b2[p]));
    if (wpad) dg_tbl4[tseg * 1024 + padf4] = make_float4(0.f, 0.f, 0.f, 0.f);
}

__global__ __launch_bounds__(256, 4) void k_main(const float* __restrict__ feat,
                                                 const float* __restrict__ geom,
                                                 const float* __restrict__ mask,
                                                 float* __restrict__ out) {
    int wv   = threadIdx.x >> 6;
    int lane = threadIdx.x & 63;
    int gw   = blockIdx.x * 4 + wv;     // 4 waves of a block share za
    int chunk = gw & (CW - 1);
    int za    = gw >> 5;                // z*160 + a
    int z     = za / NA;

    __shared__ __align__(16) float sFeat[4][PPW][64]; // slot v = {f1x,f1y,f1z,f0}
    __shared__ float sAcc[4][64];

    const bool is0 = lane < 16;
    int u  = is0 ? lane : ((lane - 16) / 3);
    int i3 = is0 ? 0 : ((lane - 16) % 3);
    int waddr = is0 ? (lane * 4 + 3) : (((lane - 16) / 3) * 4 + ((lane - 16) % 3));

    int o_base = (is0 ? 0 : 512) + u * 2;   // first float4 slot within segment row
    float zfl  = is0 ? 1.4142135623730951f : 2.0f;  // zero-radius norm ratio
    float bx = (!is0 && i3 == 0) ? 1.0f : 0.0f;
    float by = (!is0 && i3 == 1) ? 1.0f : 0.0f;
    float bz = (!is0 && i3 == 2) ? 1.0f : 0.0f;

    float thrv = dg_thr[lane];

    const float is30 = 0.18257418583505536f;  // 1/sqrt(30)
    const float is10 = 0.31622776601683794f;  // 1/sqrt(10)
    const float c1sh = 0.4886025119029199f;
    const float c21 = 1.0925484305920792f, c22 = 0.31539156525252005f, c23 = 0.5462742152960396f;

    // ---- stage all PPW feature rows (wave-private LDS slot, no barrier) ----
    int b0 = chunk * PPW;
    #pragma unroll
    for (int it = 0; it < PPW; ++it) {
        float fv = feat[((size_t)(z * NB + b0 + it)) * 64 + lane];
        sFeat[wv][it][waddr] = fv;
    }

    // ---- precompute geometry/segment for all PPW pairs ----
    float rr[PPW], nxa[PPW], nya[PPW], nza[PPW], zfa[PPW];
    int rowo[PPW];
    #pragma unroll
    for (int it = 0; it < PPW; ++it) {
        const float* g = geom + ((size_t)za * NB + b0 + it) * 3;
        float gx = g[0], gy = g[1], gz = g[2];
        float r = sqrtf(gx * gx + gy * gy + gz * gz);
        bool zr = (r == 0.0f);
        float inv = zr ? 1.0f : (1.0f / r);
        nxa[it] = gx * inv; nya[it] = gy * inv; nza[it] = gz * inv;
        rr[it] = r;
        zfa[it] = zr ? zfl : 1.0f;
        unsigned long long bm = __ballot(thrv < r);
        rowo[it] = __popcll(bm) * 1024;
    }

    float acc = 0.0f;

    #pragma unroll
    for (int it = 0; it < PPW; ++it) {
        float r = rr[it];
        float nx = nxa[it], ny = nya[it], nz = nza[it];

        // real SH (e3nn convention; l=1 order y,z,x)
        float Y1_0 = c1sh * ny, Y1_1 = c1sh * nz, Y1_2 = c1sh * nx;
        float Y2_0 = c21 * nx * ny;
        float Y2_1 = c21 * ny * nz;
        float Y2_2 = c22 * fmaf(3.0f, nz * nz, -1.0f);
        float Y2_3 = c21 * nx * nz;
        float Y2_4 = c23 * (nx * nx - ny * ny);

        // per-lane coefficient vectors (uniform inner loop):
        //  s += R0*(c0*f0) + R1*(d1.f1) + R2*(d2.f1) + R3*(d3.f1)
        // (l0 lanes: R2=R3=0 from the zero pad, so d2/d3 values are harmless)
        float Yi = (i3 == 0) ? Y1_0 : (i3 == 1) ? Y1_1 : Y1_2;
        float c0 = is0 ? 1.0f : Yi;
        float d1x = is0 ? Y1_0 : bx;
        float d1y = is0 ? Y1_1 : by;
        float d1z = is0 ? Y1_2 : bz;
        float d2x = (i3 == 0) ? 0.0f   : (i3 == 1) ? -Y1_2 : Y1_1;
        float d2y = (i3 == 0) ? Y1_2   : (i3 == 1) ? 0.0f  : -Y1_0;
        float d2z = (i3 == 0) ? -Y1_1  : (i3 == 1) ? Y1_0  : 0.0f;
        float za_ = is10 * Y2_0, zb_ = is10 * Y2_1, zc_ = is10 * Y2_3;
        float zd_ = is30 * Y2_2, ze_ = is10 * Y2_4;
        float d3x = (i3 == 0) ? (-zd_ - ze_) : (i3 == 1) ? zb_ : za_;
        float d3y = (i3 == 0) ? zb_ : (i3 == 1) ? (2.0f * zd_) : zc_;
        float d3z = (i3 == 0) ? za_ : (i3 == 1) ? zc_ : (ze_ - zd_);

        const float4* __restrict__ row = dg_tbl4 + rowo[it];
        const float*  sp = &sFeat[wv][it][0];
        int o = o_base;
        float s0 = 0.0f, s1 = 0.0f;
        #pragma unroll 8
        for (int v = 0; v < 16; ++v) {
            float4 t01 = row[o];        // {A,B} or {C,D}
            float4 t23 = row[o + 1];    // zeros  or {E,F}
            o += 32;
            float R0 = fmaf(r, t01.x, t01.y);
            float R1 = fmaf(r, t01.z, t01.w);
            float R2 = fmaf(r, t23.x, t23.y);
            float R3 = fmaf(r, t23.z, t23.w);
            float4 fq = *(const float4*)&sp[4 * v];   // {f1x,f1y,f1z,f0} broadcast
            s0 = fmaf(R0, c0 * fq.w, s0);
            float dot1 = fmaf(d1z, fq.z, fmaf(d1y, fq.y, d1x * fq.x));
            s1 = fmaf(R1, dot1, s1);
            float dot2 = fmaf(d2z, fq.z, fmaf(d2y, fq.y, d2x * fq.x));
            s0 = fmaf(R2, dot2, s0);
            float dot3 = fmaf(d3z, fq.z, fmaf(d3y, fq.y, d3x * fq.x));
            s1 = fmaf(R3, dot3, s1);
        }
        acc = fmaf(s0 + s1, zfa[it], acc);
    }

    sAcc[wv][lane] = acc;
    __syncthreads();
    if (threadIdx.x < 64) {
        float sum = sAcc[0][threadIdx.x] + sAcc[1][threadIdx.x]
                  + sAcc[2][threadIdx.x] + sAcc[3][threadIdx.x];
        sum *= mask[za];
        atomicAdd(&out[(size_t)za * 64 + threadIdx.x], sum);
    }
}

extern "C" void kernel_launch(void* const* d_in, const int* in_sizes, int n_in,
                              void* d_out, int out_size, void* d_ws, size_t ws_size,
                              hipStream_t stream) {
    (void)in_sizes; (void)n_in; (void)d_ws; (void)ws_size; (void)out_size;
    const float* feat = (const float*)d_in[0];
    const float* geom = (const float*)d_in[1];
    const float* mask = (const float*)d_in[2];
    const float* W1   = (const float*)d_in[3];
    const float* b1   = (const float*)d_in[4];
    const float* W2   = (const float*)d_in[5];
    const float* b2   = (const float*)d_in[6];
    float* out = (float*)d_out;

    k_prep<<<470, 256, 0, stream>>>(W1, b1, W2, b2, out);   // 390 table + 80 zero
    k_main<<<2 * NA * CW / 4, 256, 0, stream>>>(feat, geom, mask, out);
}

// Round 6
// 113.656 us; speedup vs baseline: 1.7584x; 1.1413x over previous
//
#include <hip/hip_runtime.h>
#include <hip/hip_fp16.h>
#include <math.h>

#define NPATH 1536
#define NSEG  65
#define NB    160
#define NA    160
#define CW    32   // chunks (waves) per (z,a)
#define PPW   5    // pairs per wave = NB/CW

// Piecewise-linear radial-MLP table, fp16-packed: one 16B entry holds a
// lane's 4 slots: {h2(s0,s1), h2(s2,s3), h2(i0,i1), h2(i2,i3)}; R_k(r) =
// r*s_k + i_k (computed in f32). Per-block Wigner/norm constants pre-folded.
// Per segment: 512 entries (8 KB): [0..255] l0 (v*16+u) -> slots {A,B,0,0};
// [256..511] l1 (v*16+u) -> slots {C,D,E,F}.
__device__ float  dg_thr[64];    // per-channel threshold -b1/W1 (inf if W1==0)
__device__ float4 dg_tbl4[NSEG * 512];

static __device__ __forceinline__ __half2 bc_h2(float x) {
    union { float f; __half2 h; } u; u.f = x; return u.h;
}
static __device__ __forceinline__ unsigned short h_us(__half h) {
    union { __half h; unsigned short s; } u; u.h = h; return u.s;
}

// blocks 0..389: table (one thread per (segment,path), direct masked sums —
// activity is a pure rank predicate, rank-sort recomputed per block).
// blocks 390..469: zero d_out.
__global__ __launch_bounds__(256) void k_prep(const float* __restrict__ W1,
                                              const float* __restrict__ b1,
                                              const float* __restrict__ W2,
                                              const float* __restrict__ b2,
                                              float* __restrict__ out) {
    int bid = blockIdx.x, tid = threadIdx.x;
    if (bid >= 390) {
        out[(bid - 390) * 256 + tid] = 0.0f;
        return;
    }
    int tseg = bid / 6, tcol = bid % 6;
    __shared__ float tv[64], mw[64], mb[64];
    if (tid < 64) {
        float w = W1[tid], b = b1[tid];
        tv[tid] = (w != 0.0f) ? (-b / w) : __builtin_inff();
    }
    __syncthreads();
    if (tid < 64) {
        float mine = tv[tid];
        int rank = 0;
        for (int j = 0; j < 64; ++j) {
            float o = tv[j];
            rank += (o < mine || (o == mine && j < tid)) ? 1 : 0;
        }
        float w = W1[tid], b = b1[tid];
        // active at segment s (= #thresholds < r):
        //   w>0: rank < s ; w<0: rank >= s ; w==0: b>0
        bool act = (w > 0.0f) ? (rank < tseg)
                 : (w < 0.0f) ? (rank >= tseg)
                              : (b > 0.0f);
        mw[tid] = act ? w : 0.0f;
        mb[tid] = act ? b : 0.0f;
        if (bid == 0) dg_thr[tid] = mine;
    }
    __syncthreads();

    int p = tcol * 256 + tid;
    int e, k; float scl;
    if (p < 768) {
        int u = (p >> 4) & 15, v = p & 15, vu = v * 16 + u;
        if (p < 256)      { e = vu;       k = 0; scl = 0.17677669529663687f; } // A
        else if (p < 512) { e = vu;       k = 1; scl = 0.6266570686577502f;  } // B
        else              { e = 256 + vu; k = 0; scl = 0.2558286876965162f;  } // C
    } else {
        int m = (p - 768) / 3, kk = (p - 768) % 3;
        int u = m >> 4, v = m & 15, vu = v * 16 + u;
        e = 256 + vu;
        if (kk == 0)      { k = 1; scl = 0.125f;              }  // D
        else if (kk == 1) { k = 2; scl = 0.3133285343288751f; }  // E
        else              { k = 3; scl = 0.7674950309598664f; }  // F
    }

    float A = 0.0f, B = 0.0f;
    #pragma unroll 8
    for (int c = 0; c < 64; ++c) {
        float w2 = W2[c * NPATH + p];   // coalesced across tid; W2 is L2-hot
        A = fmaf(mw[c], w2, A);
        B = fmaf(mb[c], w2, B);
    }
    float sv = scl * A;
    float iv = scl * (B + b2[p]);

    unsigned short* ub = (unsigned short*)dg_tbl4 + ((size_t)tseg * 512 + e) * 8;
    ub[k]     = h_us(__float2half(sv));   // slope slot k  (ushorts 0..3)
    ub[4 + k] = h_us(__float2half(iv));   // icpt  slot k  (ushorts 4..7)
    if (p < 256) {                        // A-thread zeroes the l0 pad slots 2,3
        ((unsigned int*)ub)[1] = 0u;      // s2,s3
        ((unsigned int*)ub)[3] = 0u;      // i2,i3
    }
}

__global__ __launch_bounds__(256, 4) void k_main(const float* __restrict__ feat,
                                                 const float* __restrict__ geom,
                                                 const float* __restrict__ mask,
                                                 float* __restrict__ out) {
    int wv   = threadIdx.x >> 6;
    int lane = threadIdx.x & 63;
    int gw   = blockIdx.x * 4 + wv;     // 4 waves of a block share za
    int chunk = gw & (CW - 1);
    int za    = gw >> 5;                // z*160 + a
    int z     = za / NA;

    __shared__ __align__(16) float sFeat[4][PPW][64]; // slot v = {f1x,f1y,f1z,f0}
    __shared__ float sAcc[4][64];

    const bool is0 = lane < 16;
    int u  = is0 ? lane : ((lane - 16) / 3);
    int i3 = is0 ? 0 : ((lane - 16) % 3);
    int waddr = is0 ? (lane * 4 + 3) : (((lane - 16) / 3) * 4 + ((lane - 16) % 3));

    int o_base = (is0 ? 0 : 256) + u;   // entry index within segment row
    float zfl  = is0 ? 1.4142135623730951f : 2.0f;  // zero-radius norm ratio
    float bx = (!is0 && i3 == 0) ? 1.0f : 0.0f;
    float by = (!is0 && i3 == 1) ? 1.0f : 0.0f;
    float bz = (!is0 && i3 == 2) ? 1.0f : 0.0f;

    float thrv = dg_thr[lane];

    const float is30 = 0.18257418583505536f;  // 1/sqrt(30)
    const float is10 = 0.31622776601683794f;  // 1/sqrt(10)
    const float c1sh = 0.4886025119029199f;
    const float c21 = 1.0925484305920792f, c22 = 0.31539156525252005f, c23 = 0.5462742152960396f;

    // ---- stage all PPW feature rows (wave-private LDS slot, no barrier) ----
    int b0 = chunk * PPW;
    #pragma unroll
    for (int it = 0; it < PPW; ++it) {
        float fv = feat[((size_t)(z * NB + b0 + it)) * 64 + lane];
        sFeat[wv][it][waddr] = fv;
    }

    // ---- precompute geometry/segment for all PPW pairs ----
    float rr[PPW], nxa[PPW], nya[PPW], nza[PPW], zfa[PPW];
    int rowo[PPW];
    #pragma unroll
    for (int it = 0; it < PPW; ++it) {
        const float* g = geom + ((size_t)za * NB + b0 + it) * 3;
        float gx = g[0], gy = g[1], gz = g[2];
        float r = sqrtf(gx * gx + gy * gy + gz * gz);
        bool zr = (r == 0.0f);
        float inv = zr ? 1.0f : (1.0f / r);
        nxa[it] = gx * inv; nya[it] = gy * inv; nza[it] = gz * inv;
        rr[it] = r;
        zfa[it] = zr ? zfl : 1.0f;
        unsigned long long bm = __ballot(thrv < r);
        rowo[it] = __popcll(bm) * 512;
    }

    float acc = 0.0f;

    #pragma unroll
    for (int it = 0; it < PPW; ++it) {
        float r = rr[it];
        float nx = nxa[it], ny = nya[it], nz = nza[it];

        // real SH (e3nn convention; l=1 order y,z,x)
        float Y1_0 = c1sh * ny, Y1_1 = c1sh * nz, Y1_2 = c1sh * nx;
        float Y2_0 = c21 * nx * ny;
        float Y2_1 = c21 * ny * nz;
        float Y2_2 = c22 * fmaf(3.0f, nz * nz, -1.0f);
        float Y2_3 = c21 * nx * nz;
        float Y2_4 = c23 * (nx * nx - ny * ny);

        // per-lane coefficient vectors (uniform inner loop):
        //  s += R0*(c0*f0) + R1*(d1.f1) + R2*(d2.f1) + R3*(d3.f1)
        // (l0 lanes: R2=R3=0 from the zero pad, so d2/d3 values are harmless)
        float Yi = (i3 == 0) ? Y1_0 : (i3 == 1) ? Y1_1 : Y1_2;
        float c0 = is0 ? 1.0f : Yi;
        float d1x = is0 ? Y1_0 : bx;
        float d1y = is0 ? Y1_1 : by;
        float d1z = is0 ? Y1_2 : bz;
        float d2x = (i3 == 0) ? 0.0f   : (i3 == 1) ? -Y1_2 : Y1_1;
        float d2y = (i3 == 0) ? Y1_2   : (i3 == 1) ? 0.0f  : -Y1_0;
        float d2z = (i3 == 0) ? -Y1_1  : (i3 == 1) ? Y1_0  : 0.0f;
        float za_ = is10 * Y2_0, zb_ = is10 * Y2_1, zc_ = is10 * Y2_3;
        float zd_ = is30 * Y2_2, ze_ = is10 * Y2_4;
        float d3x = (i3 == 0) ? (-zd_ - ze_) : (i3 == 1) ? zb_ : za_;
        float d3y = (i3 == 0) ? zb_ : (i3 == 1) ? (2.0f * zd_) : zc_;
        float d3z = (i3 == 0) ? za_ : (i3 == 1) ? zc_ : (ze_ - zd_);

        const float4* __restrict__ row = dg_tbl4 + rowo[it];
        const float*  sp = &sFeat[wv][it][0];
        int o = o_base;
        float s0 = 0.0f, s1 = 0.0f;
        #pragma unroll 8
        for (int v = 0; v < 16; ++v) {
            float4 t = row[o];          // {s01,s23,i01,i23} fp16-packed
            o += 16;
            __half2 hs01 = bc_h2(t.x), hs23 = bc_h2(t.y);
            __half2 hi01 = bc_h2(t.z), hi23 = bc_h2(t.w);
            float R0 = fmaf(r, __low2float(hs01),  __low2float(hi01));
            float R1 = fmaf(r, __high2float(hs01), __high2float(hi01));
            float R2 = fmaf(r, __low2float(hs23),  __low2float(hi23));
            float R3 = fmaf(r, __high2float(hs23), __high2float(hi23));
            float4 fq = *(const float4*)&sp[4 * v];   // {f1x,f1y,f1z,f0} broadcast
            s0 = fmaf(R0, c0 * fq.w, s0);
            float dot1 = fmaf(d1z, fq.z, fmaf(d1y, fq.y, d1x * fq.x));
            s1 = fmaf(R1, dot1, s1);
            float dot2 = fmaf(d2z, fq.z, fmaf(d2y, fq.y, d2x * fq.x));
            s0 = fmaf(R2, dot2, s0);
            float dot3 = fmaf(d3z, fq.z, fmaf(d3y, fq.y, d3x * fq.x));
            s1 = fmaf(R3, dot3, s1);
        }
        acc = fmaf(s0 + s1, zfa[it], acc);
    }

    sAcc[wv][lane] = acc;
    __syncthreads();
    if (threadIdx.x < 64) {
        float sum = sAcc[0][threadIdx.x] + sAcc[1][threadIdx.x]
                  + sAcc[2][threadIdx.x] + sAcc[3][threadIdx.x];
        sum *= mask[za];
        atomicAdd(&out[(size_t)za * 64 + threadIdx.x], sum);
    }
}

extern "C" void kernel_launch(void* const* d_in, const int* in_sizes, int n_in,
                              void* d_out, int out_size, void* d_ws, size_t ws_size,
                              hipStream_t stream) {
    (void)in_sizes; (void)n_in; (void)d_ws; (void)ws_size; (void)out_size;
    const float* feat = (const float*)d_in[0];
    const float* geom = (const float*)d_in[1];
    const float* mask = (const float*)d_in[2];
    const float* W1   = (const float*)d_in[3];
    const float* b1   = (const float*)d_in[4];
    const float* W2   = (const float*)d_in[5];
    const float* b2   = (const float*)d_in[6];
    float* out = (float*)d_out;

    k_prep<<<470, 256, 0, stream>>>(W1, b1, W2, b2, out);   // 390 table + 80 zero
    k_main<<<2 * NA * CW / 4, 256, 0, stream>>>(feat, geom, mask, out);
}

// Round 7
// 104.834 us; speedup vs baseline: 1.9064x; 1.0842x over previous
//
#include <hip/hip_runtime.h>
#include <hip/hip_fp16.h>
#include <math.h>

#define NPATH 1536
#define NSEG  65
#define NB    160
#define NA    160
#define CW    32   // chunks (waves) per (z,a)
#define PPW   5    // pairs per wave = NB/CW

// Piecewise-linear radial-MLP table, fp16-packed: one 16B entry holds a
// lane's 4 slots: {h2(s0,s1), h2(s2,s3), h2(i0,i1), h2(i2,i3)}; R_k(r) =
// r*s_k + i_k (computed in f32). Per-block Wigner/norm constants pre-folded.
// Per segment: 512 entries (8 KB): [0..255] l0 (v*16+u) -> slots {A,B,0,0};
// [256..511] l1 (v*16+u) -> slots {C,D,E,F}.
__device__ float  dg_thr[64];    // per-channel threshold -b1/W1 (inf if W1==0)
__device__ float4 dg_tbl4[NSEG * 512];

static __device__ __forceinline__ __half2 bc_h2(float x) {
    union { float f; __half2 h; } u; u.f = x; return u.h;
}
static __device__ __forceinline__ unsigned short h_us(__half h) {
    union { __half h; unsigned short s; } u; u.h = h; return u.s;
}

// blocks 0..389: table (one thread per (segment,path), direct masked sums —
// activity is a pure rank predicate, rank-sort recomputed per block).
// blocks 390..469: zero d_out.
__global__ __launch_bounds__(256) void k_prep(const float* __restrict__ W1,
                                              const float* __restrict__ b1,
                                              const float* __restrict__ W2,
                                              const float* __restrict__ b2,
                                              float* __restrict__ out) {
    int bid = blockIdx.x, tid = threadIdx.x;
    if (bid >= 390) {
        out[(bid - 390) * 256 + tid] = 0.0f;
        return;
    }
    int tseg = bid / 6, tcol = bid % 6;
    __shared__ float tv[64], mw[64], mb[64];
    if (tid < 64) {
        float w = W1[tid], b = b1[tid];
        tv[tid] = (w != 0.0f) ? (-b / w) : __builtin_inff();
    }
    __syncthreads();
    if (tid < 64) {
        float mine = tv[tid];
        int rank = 0;
        for (int j = 0; j < 64; ++j) {
            float o = tv[j];
            rank += (o < mine || (o == mine && j < tid)) ? 1 : 0;
        }
        float w = W1[tid], b = b1[tid];
        // active at segment s (= #thresholds < r):
        //   w>0: rank < s ; w<0: rank >= s ; w==0: b>0
        bool act = (w > 0.0f) ? (rank < tseg)
                 : (w < 0.0f) ? (rank >= tseg)
                              : (b > 0.0f);
        mw[tid] = act ? w : 0.0f;
        mb[tid] = act ? b : 0.0f;
        if (bid == 0) dg_thr[tid] = mine;
    }
    __syncthreads();

    int p = tcol * 256 + tid;
    int e, k; float scl;
    if (p < 768) {
        int u = (p >> 4) & 15, v = p & 15, vu = v * 16 + u;
        if (p < 256)      { e = vu;       k = 0; scl = 0.17677669529663687f; } // A
        else if (p < 512) { e = vu;       k = 1; scl = 0.6266570686577502f;  } // B
        else              { e = 256 + vu; k = 0; scl = 0.2558286876965162f;  } // C
    } else {
        int m = (p - 768) / 3, kk = (p - 768) % 3;
        int u = m >> 4, v = m & 15, vu = v * 16 + u;
        e = 256 + vu;
        if (kk == 0)      { k = 1; scl = 0.125f;              }  // D
        else if (kk == 1) { k = 2; scl = 0.3133285343288751f; }  // E
        else              { k = 3; scl = 0.7674950309598664f; }  // F
    }

    float A = 0.0f, B = 0.0f;
    #pragma unroll 8
    for (int c = 0; c < 64; ++c) {
        float w2 = W2[c * NPATH + p];   // coalesced across tid; W2 is L2-hot
        A = fmaf(mw[c], w2, A);
        B = fmaf(mb[c], w2, B);
    }
    float sv = scl * A;
    float iv = scl * (B + b2[p]);

    unsigned short* ub = (unsigned short*)dg_tbl4 + ((size_t)tseg * 512 + e) * 8;
    ub[k]     = h_us(__float2half(sv));   // slope slot k  (ushorts 0..3)
    ub[4 + k] = h_us(__float2half(iv));   // icpt  slot k  (ushorts 4..7)
    if (p < 256) {                        // A-thread zeroes the l0 pad slots 2,3
        ((unsigned int*)ub)[1] = 0u;      // s2,s3
        ((unsigned int*)ub)[3] = 0u;      // i2,i3
    }
}

__global__ __launch_bounds__(256, 4) void k_main(const float* __restrict__ feat,
                                                 const float* __restrict__ geom,
                                                 const float* __restrict__ mask,
                                                 float* __restrict__ out) {
    int wv   = threadIdx.x >> 6;
    int lane = threadIdx.x & 63;
    int gw   = blockIdx.x * 4 + wv;     // 4 waves of a block share za
    int chunk = gw & (CW - 1);
    int za    = gw >> 5;                // z*160 + a
    int z     = za / NA;

    __shared__ __align__(16) float sFeat[4][PPW][64]; // slot v = {f1x,f1y,f1z,f0}
    __shared__ float sAcc[4][64];

    const bool is0 = lane < 16;
    int u  = is0 ? lane : ((lane - 16) / 3);
    int i3 = is0 ? 0 : ((lane - 16) % 3);
    int waddr = is0 ? (lane * 4 + 3) : (((lane - 16) / 3) * 4 + ((lane - 16) % 3));

    int o_base = (is0 ? 0 : 256) + u;   // entry index within segment row
    float zfl  = is0 ? 1.4142135623730951f : 2.0f;  // zero-radius norm ratio
    float bx = (!is0 && i3 == 0) ? 1.0f : 0.0f;
    float by = (!is0 && i3 == 1) ? 1.0f : 0.0f;
    float bz = (!is0 && i3 == 2) ? 1.0f : 0.0f;

    float thrv = dg_thr[lane];

    const float is30 = 0.18257418583505536f;  // 1/sqrt(30)
    const float is10 = 0.31622776601683794f;  // 1/sqrt(10)
    const float c1sh = 0.4886025119029199f;
    const float c21 = 1.0925484305920792f, c22 = 0.31539156525252005f, c23 = 0.5462742152960396f;

    // ---- stage all PPW feature rows (wave-private LDS slot, no barrier) ----
    int b0 = chunk * PPW;
    #pragma unroll
    for (int it = 0; it < PPW; ++it) {
        float fv = feat[((size_t)(z * NB + b0 + it)) * 64 + lane];
        sFeat[wv][it][waddr] = fv;
    }

    // ---- precompute geometry/segment for all PPW pairs ----
    float rr[PPW], nxa[PPW], nya[PPW], nza[PPW], zfa[PPW];
    int rowo[PPW];
    #pragma unroll
    for (int it = 0; it < PPW; ++it) {
        const float* g = geom + ((size_t)za * NB + b0 + it) * 3;
        float gx = g[0], gy = g[1], gz = g[2];
        float r = sqrtf(gx * gx + gy * gy + gz * gz);
        bool zr = (r == 0.0f);
        float inv = zr ? 1.0f : (1.0f / r);
        nxa[it] = gx * inv; nya[it] = gy * inv; nza[it] = gz * inv;
        rr[it] = r;
        zfa[it] = zr ? zfl : 1.0f;
        unsigned long long bm = __ballot(thrv < r);
        rowo[it] = __popcll(bm) * 512;
    }

    float acc = 0.0f;

    #pragma unroll
    for (int it = 0; it < PPW; ++it) {
        float r = rr[it];

        // ---- inner v-loop: only R-evals + factored accumulators ----
        //   T0   = sum_v R0*f0      T1 = sum_v R1*f1   (vector, xyz)
        //   T2   = sum_v R2*f1      T3 = sum_v R3*f1
        // (coefficient vectors applied once in the epilogue below)
        const float4* __restrict__ rowp = dg_tbl4 + rowo[it] + o_base;
        const float*  sp = &sFeat[wv][it][0];
        float T0 = 0.0f;
        float T1x = 0.0f, T1y = 0.0f, T1z = 0.0f;
        float T2x = 0.0f, T2y = 0.0f, T2z = 0.0f;
        float T3x = 0.0f, T3y = 0.0f, T3z = 0.0f;
        #pragma unroll
        for (int v = 0; v < 16; ++v) {
            float4 t = rowp[v * 16];    // {s01,s23,i01,i23} fp16-packed
            __half2 hs01 = bc_h2(t.x), hs23 = bc_h2(t.y);
            __half2 hi01 = bc_h2(t.z), hi23 = bc_h2(t.w);
            float R0 = fmaf(r, __low2float(hs01),  __low2float(hi01));
            float R1 = fmaf(r, __high2float(hs01), __high2float(hi01));
            float R2 = fmaf(r, __low2float(hs23),  __low2float(hi23));
            float R3 = fmaf(r, __high2float(hs23), __high2float(hi23));
            float4 fq = *(const float4*)&sp[4 * v];   // {f1x,f1y,f1z,f0} broadcast
            T0  = fmaf(R0, fq.w, T0);
            T1x = fmaf(R1, fq.x, T1x);
            T1y = fmaf(R1, fq.y, T1y);
            T1z = fmaf(R1, fq.z, T1z);
            T2x = fmaf(R2, fq.x, T2x);
            T2y = fmaf(R2, fq.y, T2y);
            T2z = fmaf(R2, fq.z, T2z);
            T3x = fmaf(R3, fq.x, T3x);
            T3y = fmaf(R3, fq.y, T3y);
            T3z = fmaf(R3, fq.z, T3z);
        }

        // ---- epilogue: build coefficient vectors, contract, rescale ----
        float nx = nxa[it], ny = nya[it], nz = nza[it];
        // real SH (e3nn convention; l=1 order y,z,x)
        float Y1_0 = c1sh * ny, Y1_1 = c1sh * nz, Y1_2 = c1sh * nx;
        float Y2_0 = c21 * nx * ny;
        float Y2_1 = c21 * ny * nz;
        float Y2_2 = c22 * fmaf(3.0f, nz * nz, -1.0f);
        float Y2_3 = c21 * nx * nz;
        float Y2_4 = c23 * (nx * nx - ny * ny);

        float Yi = (i3 == 0) ? Y1_0 : (i3 == 1) ? Y1_1 : Y1_2;
        float c0 = is0 ? 1.0f : Yi;
        float d1x = is0 ? Y1_0 : bx;
        float d1y = is0 ? Y1_1 : by;
        float d1z = is0 ? Y1_2 : bz;
        // (l0 lanes: T2=T3=0 from the zero pad, so d2/d3 values are harmless)
        float d2x = (i3 == 0) ? 0.0f   : (i3 == 1) ? -Y1_2 : Y1_1;
        float d2y = (i3 == 0) ? Y1_2   : (i3 == 1) ? 0.0f  : -Y1_0;
        float d2z = (i3 == 0) ? -Y1_1  : (i3 == 1) ? Y1_0  : 0.0f;
        float za_ = is10 * Y2_0, zb_ = is10 * Y2_1, zc_ = is10 * Y2_3;
        float zd_ = is30 * Y2_2, ze_ = is10 * Y2_4;
        float d3x = (i3 == 0) ? (-zd_ - ze_) : (i3 == 1) ? zb_ : za_;
        float d3y = (i3 == 0) ? zb_ : (i3 == 1) ? (2.0f * zd_) : zc_;
        float d3z = (i3 == 0) ? za_ : (i3 == 1) ? zc_ : (ze_ - zd_);

        float s = c0 * T0;
        s = fmaf(d1x, T1x, s); s = fmaf(d1y, T1y, s); s = fmaf(d1z, T1z, s);
        s = fmaf(d2x, T2x, s); s = fmaf(d2y, T2y, s); s = fmaf(d2z, T2z, s);
        s = fmaf(d3x, T3x, s); s = fmaf(d3y, T3y, s); s = fmaf(d3z, T3z, s);
        acc = fmaf(s, zfa[it], acc);
    }

    sAcc[wv][lane] = acc;
    __syncthreads();
    if (threadIdx.x < 64) {
        float sum = sAcc[0][threadIdx.x] + sAcc[1][threadIdx.x]
                  + sAcc[2][threadIdx.x] + sAcc[3][threadIdx.x];
        sum *= mask[za];
        atomicAdd(&out[(size_t)za * 64 + threadIdx.x], sum);
    }
}

extern "C" void kernel_launch(void* const* d_in, const int* in_sizes, int n_in,
                              void* d_out, int out_size, void* d_ws, size_t ws_size,
                              hipStream_t stream) {
    (void)in_sizes; (void)n_in; (void)d_ws; (void)ws_size; (void)out_size;
    const float* feat = (const float*)d_in[0];
    const float* geom = (const float*)d_in[1];
    const float* mask = (const float*)d_in[2];
    const float* W1   = (const float*)d_in[3];
    const float* b1   = (const float*)d_in[4];
    const float* W2   = (const float*)d_in[5];
    const float* b2   = (const float*)d_in[6];
    float* out = (float*)d_out;

    k_prep<<<470, 256, 0, stream>>>(W1, b1, W2, b2, out);   // 390 table + 80 zero
    k_main<<<2 * NA * CW / 4, 256, 0, stream>>>(feat, geom, mask, out);
}

// Round 8
// 96.587 us; speedup vs baseline: 2.0692x; 1.0854x over previous
//
#include <hip/hip_runtime.h>
#include <hip/hip_fp16.h>
#include <math.h>

#define NPATH 1536
#define NSEG  65
#define NB    160
#define NA    160
#define CW    32   // chunks (waves) per (z,a)
#define PPW   5    // pairs per wave = NB/CW

// Piecewise-linear radial-MLP table, fp16-packed: one 16B entry holds a
// lane's 4 slots: {h2(s0,s1), h2(s2,s3), h2(i0,i1), h2(i2,i3)}; R_k(r) =
// r*s_k + i_k (computed in f32). Per-block Wigner/norm constants pre-folded.
// Per segment: 512 entries (8 KB): [0..255] l0 (v*16+u) -> slots {A,B,0,0};
// [256..511] l1 (v*16+u) -> slots {C,D,E,F}.
__device__ float  dg_thr[64];    // per-channel threshold -b1/W1 (inf if W1==0)
__device__ float4 dg_tbl4[NSEG * 512];

static __device__ __forceinline__ __half2 bc_h2(float x) {
    union { float f; __half2 h; } u; u.f = x; return u.h;
}
static __device__ __forceinline__ unsigned short h_us(__half h) {
    union { __half h; unsigned short s; } u; u.h = h; return u.s;
}

// blocks 0..389: table (one thread per (segment,path), direct masked sums —
// activity is a pure rank predicate, rank-sort recomputed per block).
// blocks 390..469: zero d_out.
__global__ __launch_bounds__(256) void k_prep(const float* __restrict__ W1,
                                              const float* __restrict__ b1,
                                              const float* __restrict__ W2,
                                              const float* __restrict__ b2,
                                              float* __restrict__ out) {
    int bid = blockIdx.x, tid = threadIdx.x;
    if (bid >= 390) {
        out[(bid - 390) * 256 + tid] = 0.0f;
        return;
    }
    int tseg = bid / 6, tcol = bid % 6;
    __shared__ float tv[64], mw[64], mb[64];
    if (tid < 64) {
        float w = W1[tid], b = b1[tid];
        tv[tid] = (w != 0.0f) ? (-b / w) : __builtin_inff();
    }
    __syncthreads();
    if (tid < 64) {
        float mine = tv[tid];
        int rank = 0;
        for (int j = 0; j < 64; ++j) {
            float o = tv[j];
            rank += (o < mine || (o == mine && j < tid)) ? 1 : 0;
        }
        float w = W1[tid], b = b1[tid];
        // active at segment s (= #thresholds < r):
        //   w>0: rank < s ; w<0: rank >= s ; w==0: b>0
        bool act = (w > 0.0f) ? (rank < tseg)
                 : (w < 0.0f) ? (rank >= tseg)
                              : (b > 0.0f);
        mw[tid] = act ? w : 0.0f;
        mb[tid] = act ? b : 0.0f;
        if (bid == 0) dg_thr[tid] = mine;
    }
    __syncthreads();

    int p = tcol * 256 + tid;
    int e, k; float scl;
    if (p < 768) {
        int u = (p >> 4) & 15, v = p & 15, vu = v * 16 + u;
        if (p < 256)      { e = vu;       k = 0; scl = 0.17677669529663687f; } // A
        else if (p < 512) { e = vu;       k = 1; scl = 0.6266570686577502f;  } // B
        else              { e = 256 + vu; k = 0; scl = 0.2558286876965162f;  } // C
    } else {
        int m = (p - 768) / 3, kk = (p - 768) % 3;
        int u = m >> 4, v = m & 15, vu = v * 16 + u;
        e = 256 + vu;
        if (kk == 0)      { k = 1; scl = 0.125f;              }  // D
        else if (kk == 1) { k = 2; scl = 0.3133285343288751f; }  // E
        else              { k = 3; scl = 0.7674950309598664f; }  // F
    }

    float A = 0.0f, B = 0.0f;
    #pragma unroll 8
    for (int c = 0; c < 64; ++c) {
        float w2 = W2[c * NPATH + p];   // coalesced across tid; W2 is L2-hot
        A = fmaf(mw[c], w2, A);
        B = fmaf(mb[c], w2, B);
    }
    float sv = scl * A;
    float iv = scl * (B + b2[p]);

    unsigned short* ub = (unsigned short*)dg_tbl4 + ((size_t)tseg * 512 + e) * 8;
    ub[k]     = h_us(__float2half(sv));   // slope slot k  (ushorts 0..3)
    ub[4 + k] = h_us(__float2half(iv));   // icpt  slot k  (ushorts 4..7)
    if (p < 256) {                        // A-thread zeroes the l0 pad slots 2,3
        ((unsigned int*)ub)[1] = 0u;      // s2,s3
        ((unsigned int*)ub)[3] = 0u;      // i2,i3
    }
}

__global__ __launch_bounds__(256, 4) void k_main(const float* __restrict__ feat,
                                                 const float* __restrict__ geom,
                                                 const float* __restrict__ mask,
                                                 float* __restrict__ out) {
    int wv   = threadIdx.x >> 6;
    int lane = threadIdx.x & 63;
    int gw   = blockIdx.x * 4 + wv;     // 4 waves of a block share za
    int chunk = gw & (CW - 1);
    int za    = gw >> 5;                // z*160 + a
    int z     = za / NA;

    __shared__ __align__(16) float sFeat[4][PPW][64]; // slot v = {f1x,f1y,f1z,f0}
    __shared__ float sAcc[4][64];

    // ---- v-split task assignment (dedup: 32 tasks x 2 v-halves) ----
    int h    = lane >> 5;          // which v-half this lane accumulates
    int l32  = lane & 31;
    bool tl0 = l32 < 16;           // task type: l0 (A/B) vs l1 (C/D/E/F)
    int  tu  = l32 & 15;           // task u
    int  e_base = (tl0 ? 0 : 256) + h * 16 + tu;   // entry idx of (v=h, u)

    // ---- output assignment (after T-combine) ----
    bool is0o = lane < 16;
    int  grp  = lane >> 4;                              // 0..3
    int  i3o  = (grp == 2) ? 2 : (grp == 3) ? 1 : 0;    // 16-31:(u,0) 32-47:(u,2) 48-63:(u,1)
    int  uo   = lane & 15;
    int  outI = is0o ? uo : (16 + uo * 3 + i3o);
    bool useSw = (grp == 2);       // lanes 32-47 take the shfl48 (l1) T
    float zfl = is0o ? 1.4142135623730951f : 2.0f;  // zero-radius norm ratio
    float bx = (i3o == 0) ? 1.0f : 0.0f;
    float by = (i3o == 1) ? 1.0f : 0.0f;
    float bz = (i3o == 2) ? 1.0f : 0.0f;

    // input staging address (same layout as before)
    int waddr = (lane < 16) ? (lane * 4 + 3)
                            : (((lane - 16) / 3) * 4 + ((lane - 16) % 3));

    float thrv = dg_thr[lane];

    const float is30 = 0.18257418583505536f;  // 1/sqrt(30)
    const float is10 = 0.31622776601683794f;  // 1/sqrt(10)
    const float c1sh = 0.4886025119029199f;
    const float c21 = 1.0925484305920792f, c22 = 0.31539156525252005f, c23 = 0.5462742152960396f;

    // ---- stage all PPW feature rows (wave-private LDS slot, no barrier) ----
    int b0 = chunk * PPW;
    #pragma unroll
    for (int it = 0; it < PPW; ++it) {
        float fv = feat[((size_t)(z * NB + b0 + it)) * 64 + lane];
        sFeat[wv][it][waddr] = fv;
    }

    // ---- precompute geometry/segment for all PPW pairs ----
    float rr[PPW], nxa[PPW], nya[PPW], nza[PPW], zfa[PPW];
    int rowo[PPW];
    #pragma unroll
    for (int it = 0; it < PPW; ++it) {
        const float* g = geom + ((size_t)za * NB + b0 + it) * 3;
        float gx = g[0], gy = g[1], gz = g[2];
        float r = sqrtf(gx * gx + gy * gy + gz * gz);
        bool zr = (r == 0.0f);
        float inv = zr ? 1.0f : (1.0f / r);
        nxa[it] = gx * inv; nya[it] = gy * inv; nza[it] = gz * inv;
        rr[it] = r;
        zfa[it] = zr ? zfl : 1.0f;
        unsigned long long bm = __ballot(thrv < r);
        rowo[it] = __popcll(bm) * 512;
    }

    float acc = 0.0f;

    #pragma unroll
    for (int it = 0; it < PPW; ++it) {
        float r = rr[it];

        // ---- inner loop: 8 steps, 2 v per step (one per half-wave).
        // Every lane loads a UNIQUE table entry (zero duplication).
        const float4* __restrict__ rowp = dg_tbl4 + rowo[it] + e_base;
        const float*  spL = &sFeat[wv][it][0] + h * 4;   // this half's v features
        float T0 = 0.0f;
        float T1x = 0.0f, T1y = 0.0f, T1z = 0.0f;
        float T2x = 0.0f, T2y = 0.0f, T2z = 0.0f;
        float T3x = 0.0f, T3y = 0.0f, T3z = 0.0f;
        #pragma unroll
        for (int s = 0; s < 8; ++s) {
            float4 t = rowp[s * 32];    // {s01,s23,i01,i23} fp16-packed
            __half2 hs01 = bc_h2(t.x), hs23 = bc_h2(t.y);
            __half2 hi01 = bc_h2(t.z), hi23 = bc_h2(t.w);
            float R0 = fmaf(r, __low2float(hs01),  __low2float(hi01));
            float R1 = fmaf(r, __high2float(hs01), __high2float(hi01));
            float R2 = fmaf(r, __low2float(hs23),  __low2float(hi23));
            float R3 = fmaf(r, __high2float(hs23), __high2float(hi23));
            float4 fq = *(const float4*)&spL[s * 8];  // {f1x,f1y,f1z,f0} for v=2s+h
            T0  = fmaf(R0, fq.w, T0);
            T1x = fmaf(R1, fq.x, T1x);
            T1y = fmaf(R1, fq.y, T1y);
            T1z = fmaf(R1, fq.z, T1z);
            T2x = fmaf(R2, fq.x, T2x);
            T2y = fmaf(R2, fq.y, T2y);
            T2z = fmaf(R2, fq.z, T2z);
            T3x = fmaf(R3, fq.x, T3x);
            T3y = fmaf(R3, fq.y, T3y);
            T3z = fmaf(R3, fq.z, T3z);
        }

        // ---- combine the two v-halves; route l1 T to lanes 32-47 ----
        #define COMB(t) { t += __shfl_xor(t, 32); float _w = __shfl_xor(t, 48); t = useSw ? _w : t; }
        COMB(T0)
        COMB(T1x) COMB(T1y) COMB(T1z)
        COMB(T2x) COMB(T2y) COMB(T2z)
        COMB(T3x) COMB(T3y) COMB(T3z)
        #undef COMB

        // ---- epilogue: coefficient vectors for this lane's OUTPUT ----
        float nx = nxa[it], ny = nya[it], nz = nza[it];
        // real SH (e3nn convention; l=1 order y,z,x)
        float Y1_0 = c1sh * ny, Y1_1 = c1sh * nz, Y1_2 = c1sh * nx;
        float Y2_0 = c21 * nx * ny;
        float Y2_1 = c21 * ny * nz;
        float Y2_2 = c22 * fmaf(3.0f, nz * nz, -1.0f);
        float Y2_3 = c21 * nx * nz;
        float Y2_4 = c23 * (nx * nx - ny * ny);

        float Yi = (i3o == 0) ? Y1_0 : (i3o == 1) ? Y1_1 : Y1_2;
        float c0 = is0o ? 1.0f : Yi;
        float d1x = is0o ? Y1_0 : bx;
        float d1y = is0o ? Y1_1 : by;
        float d1z = is0o ? Y1_2 : bz;
        // (l0 output lanes: their T2/T3 are zero, so d2/d3 are harmless)
        float d2x = (i3o == 0) ? 0.0f   : (i3o == 1) ? -Y1_2 : Y1_1;
        float d2y = (i3o == 0) ? Y1_2   : (i3o == 1) ? 0.0f  : -Y1_0;
        float d2z = (i3o == 0) ? -Y1_1  : (i3o == 1) ? Y1_0  : 0.0f;
        float za_ = is10 * Y2_0, zb_ = is10 * Y2_1, zc_ = is10 * Y2_3;
        float zd_ = is30 * Y2_2, ze_ = is10 * Y2_4;
        float d3x = (i3o == 0) ? (-zd_ - ze_) : (i3o == 1) ? zb_ : za_;
        float d3y = (i3o == 0) ? zb_ : (i3o == 1) ? (2.0f * zd_) : zc_;
        float d3z = (i3o == 0) ? za_ : (i3o == 1) ? zc_ : (ze_ - zd_);

        float s = c0 * T0;
        s = fmaf(d1x, T1x, s); s = fmaf(d1y, T1y, s); s = fmaf(d1z, T1z, s);
        s = fmaf(d2x, T2x, s); s = fmaf(d2y, T2y, s); s = fmaf(d2z, T2z, s);
        s = fmaf(d3x, T3x, s); s = fmaf(d3y, T3y, s); s = fmaf(d3z, T3z, s);
        acc = fmaf(s, zfa[it], acc);
    }

    sAcc[wv][outI] = acc;
    __syncthreads();
    if (threadIdx.x < 64) {
        float sum = sAcc[0][threadIdx.x] + sAcc[1][threadIdx.x]
                  + sAcc[2][threadIdx.x] + sAcc[3][threadIdx.x];
        sum *= mask[za];
        atomicAdd(&out[(size_t)za * 64 + threadIdx.x], sum);
    }
}

extern "C" void kernel_launch(void* const* d_in, const int* in_sizes, int n_in,
                              void* d_out, int out_size, void* d_ws, size_t ws_size,
                              hipStream_t stream) {
    (void)in_sizes; (void)n_in; (void)d_ws; (void)ws_size; (void)out_size;
    const float* feat = (const float*)d_in[0];
    const float* geom = (const float*)d_in[1];
    const float* mask = (const float*)d_in[2];
    const float* W1   = (const float*)d_in[3];
    const float* b1   = (const float*)d_in[4];
    const float* W2   = (const float*)d_in[5];
    const float* b2   = (const float*)d_in[6];
    float* out = (float*)d_out;

    k_prep<<<470, 256, 0, stream>>>(W1, b1, W2, b2, out);   // 390 table + 80 zero
    k_main<<<2 * NA * CW / 4, 256, 0, stream>>>(feat, geom, mask, out);
}

// Round 9
// 93.376 us; speedup vs baseline: 2.1403x; 1.0344x over previous
//
#include <hip/hip_runtime.h>
#include <hip/hip_fp16.h>
#include <math.h>

#define NPATH 1536
#define NSEG  65
#define NB    160
#define NA    160
#define CW    32   // chunks (waves) per (z,a)
#define PPW   5    // pairs per wave = NB/CW

// Piecewise-linear radial-MLP table, fp16-packed: one 16B entry holds a
// lane's 4 slots: {h2(s0,s1), h2(s2,s3), h2(i0,i1), h2(i2,i3)}; R_k(r) =
// r*s_k + i_k (computed in f32). Per-block Wigner/norm constants pre-folded.
// Per segment: 512 entries (8 KB): [0..255] l0 (v*16+u) -> slots {A,B,0,0};
// [256..511] l1 (v*16+u) -> slots {C,D,E,F}.
__device__ float  dg_thr[64];    // per-channel threshold -b1/W1 (inf if W1==0)
__device__ float4 dg_tbl4[NSEG * 512];

static __device__ __forceinline__ __half2 bc_h2(float x) {
    union { float f; __half2 h; } u; u.f = x; return u.h;
}
static __device__ __forceinline__ unsigned short h_us(__half h) {
    union { __half h; unsigned short s; } u; u.h = h; return u.s;
}

// blocks 0..389: table (one thread per (segment,path), direct masked sums —
// activity is a pure rank predicate, rank-sort recomputed per block).
// blocks 390..469: zero d_out.
__global__ __launch_bounds__(256) void k_prep(const float* __restrict__ W1,
                                              const float* __restrict__ b1,
                                              const float* __restrict__ W2,
                                              const float* __restrict__ b2,
                                              float* __restrict__ out) {
    int bid = blockIdx.x, tid = threadIdx.x;
    if (bid >= 390) {
        out[(bid - 390) * 256 + tid] = 0.0f;
        return;
    }
    int tseg = bid / 6, tcol = bid % 6;
    __shared__ float tv[64], mw[64], mb[64];
    if (tid < 64) {
        float w = W1[tid], b = b1[tid];
        tv[tid] = (w != 0.0f) ? (-b / w) : __builtin_inff();
    }
    __syncthreads();
    if (tid < 64) {
        float mine = tv[tid];
        int rank = 0;
        for (int j = 0; j < 64; ++j) {
            float o = tv[j];
            rank += (o < mine || (o == mine && j < tid)) ? 1 : 0;
        }
        float w = W1[tid], b = b1[tid];
        // active at segment s (= #thresholds < r):
        //   w>0: rank < s ; w<0: rank >= s ; w==0: b>0
        bool act = (w > 0.0f) ? (rank < tseg)
                 : (w < 0.0f) ? (rank >= tseg)
                              : (b > 0.0f);
        mw[tid] = act ? w : 0.0f;
        mb[tid] = act ? b : 0.0f;
        if (bid == 0) dg_thr[tid] = mine;
    }
    __syncthreads();

    int p = tcol * 256 + tid;
    int e, k; float scl;
    if (p < 768) {
        int u = (p >> 4) & 15, v = p & 15, vu = v * 16 + u;
        if (p < 256)      { e = vu;       k = 0; scl = 0.17677669529663687f; } // A
        else if (p < 512) { e = vu;       k = 1; scl = 0.6266570686577502f;  } // B
        else              { e = 256 + vu; k = 0; scl = 0.2558286876965162f;  } // C
    } else {
        int m = (p - 768) / 3, kk = (p - 768) % 3;
        int u = m >> 4, v = m & 15, vu = v * 16 + u;
        e = 256 + vu;
        if (kk == 0)      { k = 1; scl = 0.125f;              }  // D
        else if (kk == 1) { k = 2; scl = 0.3133285343288751f; }  // E
        else              { k = 3; scl = 0.7674950309598664f; }  // F
    }

    float A = 0.0f, B = 0.0f;
    #pragma unroll 8
    for (int c = 0; c < 64; ++c) {
        float w2 = W2[c * NPATH + p];   // coalesced across tid; W2 is L2-hot
        A = fmaf(mw[c], w2, A);
        B = fmaf(mb[c], w2, B);
    }
    float sv = scl * A;
    float iv = scl * (B + b2[p]);

    unsigned short* ub = (unsigned short*)dg_tbl4 + ((size_t)tseg * 512 + e) * 8;
    ub[k]     = h_us(__float2half(sv));   // slope slot k  (ushorts 0..3)
    ub[4 + k] = h_us(__float2half(iv));   // icpt  slot k  (ushorts 4..7)
    if (p < 256) {                        // A-thread zeroes the l0 pad slots 2,3
        ((unsigned int*)ub)[1] = 0u;      // s2,s3
        ((unsigned int*)ub)[3] = 0u;      // i2,i3
    }
}

__global__ __launch_bounds__(256, 4) void k_main(const float* __restrict__ feat,
                                                 const float* __restrict__ geom,
                                                 const float* __restrict__ mask,
                                                 float* __restrict__ out) {
    int wv   = threadIdx.x >> 6;
    int lane = threadIdx.x & 63;
    int gw   = blockIdx.x * 4 + wv;     // 4 waves of a block share za
    int chunk = gw & (CW - 1);
    int za    = gw >> 5;                // z*160 + a
    int z     = za / NA;

    __shared__ __align__(16) float sFeat[4][PPW][64]; // slot v = {f1x,f1y,f1z,f0}
    __shared__ float sAcc[4][64];

    // ---- v-split task assignment (dedup: 32 tasks x 2 v-halves) ----
    int h    = lane >> 5;          // which v-half this lane accumulates
    int l32  = lane & 31;
    bool tl0 = l32 < 16;           // task type: l0 (A/B) vs l1 (C/D/E/F)
    int  tu  = l32 & 15;           // task u
    int  e_base = (tl0 ? 0 : 256) + h * 16 + tu;   // entry idx of (v=h, u)
    float zft = tl0 ? 1.4142135623730951f : 2.0f;  // zero-radius norm ratio (task)

    // input staging address (same layout as before)
    int waddr = (lane < 16) ? (lane * 4 + 3)
                            : (((lane - 16) / 3) * 4 + ((lane - 16) % 3));

    float thrv = dg_thr[lane];

    const float is30 = 0.18257418583505536f;  // 1/sqrt(30)
    const float is10 = 0.31622776601683794f;  // 1/sqrt(10)
    const float c1sh = 0.4886025119029199f;
    const float c21 = 1.0925484305920792f, c22 = 0.31539156525252005f, c23 = 0.5462742152960396f;

    // ---- stage all PPW feature rows (wave-private LDS slot, no barrier) ----
    int b0 = chunk * PPW;
    #pragma unroll
    for (int it = 0; it < PPW; ++it) {
        float fv = feat[((size_t)(z * NB + b0 + it)) * 64 + lane];
        sFeat[wv][it][waddr] = fv;
    }

    // ---- precompute geometry/segment for all PPW pairs ----
    float rr[PPW], nxa[PPW], nya[PPW], nza[PPW], zfa[PPW];
    int rowo[PPW];
    #pragma unroll
    for (int it = 0; it < PPW; ++it) {
        const float* g = geom + ((size_t)za * NB + b0 + it) * 3;
        float gx = g[0], gy = g[1], gz = g[2];
        float r = sqrtf(gx * gx + gy * gy + gz * gz);
        bool zr = (r == 0.0f);
        float inv = zr ? 1.0f : (1.0f / r);
        nxa[it] = gx * inv; nya[it] = gy * inv; nza[it] = gz * inv;
        rr[it] = r;
        zfa[it] = zr ? zft : 1.0f;
        unsigned long long bm = __ballot(thrv < r);
        rowo[it] = __popcll(bm) * 512;
    }

    // per-task output accumulators: l0 task -> acc0; l1 task -> acc0/1/2 = s_x/y/z
    float acc0 = 0.0f, acc1 = 0.0f, acc2 = 0.0f;

    #pragma unroll
    for (int it = 0; it < PPW; ++it) {
        float r = rr[it];

        // ---- inner loop: 8 steps, 2 v per step (one per half-wave).
        // Every lane loads a UNIQUE table entry (zero duplication).
        const float4* __restrict__ rowp = dg_tbl4 + rowo[it] + e_base;
        const float*  spL = &sFeat[wv][it][0] + h * 4;   // this half's v features
        float T0 = 0.0f;
        float T1x = 0.0f, T1y = 0.0f, T1z = 0.0f;
        float T2x = 0.0f, T2y = 0.0f, T2z = 0.0f;
        float T3x = 0.0f, T3y = 0.0f, T3z = 0.0f;
        #pragma unroll
        for (int s = 0; s < 8; ++s) {
            float4 t = rowp[s * 32];    // {s01,s23,i01,i23} fp16-packed
            __half2 hs01 = bc_h2(t.x), hs23 = bc_h2(t.y);
            __half2 hi01 = bc_h2(t.z), hi23 = bc_h2(t.w);
            float R0 = fmaf(r, __low2float(hs01),  __low2float(hi01));
            float R1 = fmaf(r, __high2float(hs01), __high2float(hi01));
            float R2 = fmaf(r, __low2float(hs23),  __low2float(hi23));
            float R3 = fmaf(r, __high2float(hs23), __high2float(hi23));
            float4 fq = *(const float4*)&spL[s * 8];  // {f1x,f1y,f1z,f0} for v=2s+h
            T0  = fmaf(R0, fq.w, T0);
            T1x = fmaf(R1, fq.x, T1x);
            T1y = fmaf(R1, fq.y, T1y);
            T1z = fmaf(R1, fq.z, T1z);
            T2x = fmaf(R2, fq.x, T2x);
            T2y = fmaf(R2, fq.y, T2y);
            T2z = fmaf(R2, fq.z, T2z);
            T3x = fmaf(R3, fq.x, T3x);
            T3y = fmaf(R3, fq.y, T3y);
            T3z = fmaf(R3, fq.z, T3z);
        }

        // ---- per-task contraction (no cross-lane traffic) ----
        float nx = nxa[it], ny = nya[it], nz = nza[it];
        // real SH (e3nn convention; l=1 order y,z,x)
        float Y1_0 = c1sh * ny, Y1_1 = c1sh * nz, Y1_2 = c1sh * nx;
        float Y2_0 = c21 * nx * ny;
        float Y2_1 = c21 * ny * nz;
        float Y2_2 = c22 * fmaf(3.0f, nz * nz, -1.0f);
        float Y2_3 = c21 * nx * nz;
        float Y2_4 = c23 * (nx * nx - ny * ny);
        float za_ = is10 * Y2_0, zb_ = is10 * Y2_1, zc_ = is10 * Y2_3;
        float zd_ = is30 * Y2_2, ze_ = is10 * Y2_4;

        // l0 task: s = T0 + Y1.T1   (slots A,B; T2/T3 are zero)
        float sl0 = T0;
        sl0 = fmaf(Y1_0, T1x, sl0);
        sl0 = fmaf(Y1_1, T1y, sl0);
        sl0 = fmaf(Y1_2, T1z, sl0);

        // l1 task, output i: s_i = Y1_i*T0 + T1_i + cross_i(T2) + Z_i(T3)
        float sx = fmaf(Y1_0, T0, T1x);
        sx = fmaf(Y1_2, T2y, sx); sx = fmaf(-Y1_1, T2z, sx);
        sx = fmaf(-(zd_ + ze_), T3x, sx); sx = fmaf(zb_, T3y, sx); sx = fmaf(za_, T3z, sx);

        float sy = fmaf(Y1_1, T0, T1y);
        sy = fmaf(-Y1_2, T2x, sy); sy = fmaf(Y1_0, T2z, sy);
        sy = fmaf(zb_, T3x, sy); sy = fmaf(2.0f * zd_, T3y, sy); sy = fmaf(zc_, T3z, sy);

        float sz = fmaf(Y1_2, T0, T1z);
        sz = fmaf(Y1_1, T2x, sz); sz = fmaf(-Y1_0, T2y, sz);
        sz = fmaf(za_, T3x, sz); sz = fmaf(zc_, T3y, sz); sz = fmaf(ze_ - zd_, T3z, sz);

        float s0 = tl0 ? sl0 : sx;
        float zf = zfa[it];
        acc0 = fmaf(s0, zf, acc0);
        acc1 = fmaf(sy, zf, acc1);
        acc2 = fmaf(sz, zf, acc2);
    }

    // ---- combine the two v-halves: 3 shuffles total ----
    acc0 += __shfl_xor(acc0, 32);
    acc1 += __shfl_xor(acc1, 32);
    acc2 += __shfl_xor(acc2, 32);

    if (lane < 32) {
        if (tl0) {
            sAcc[wv][tu] = acc0;
        } else {
            int ob = 16 + tu * 3;
            sAcc[wv][ob]     = acc0;
            sAcc[wv][ob + 1] = acc1;
            sAcc[wv][ob + 2] = acc2;
        }
    }
    __syncthreads();
    if (threadIdx.x < 64) {
        float sum = sAcc[0][threadIdx.x] + sAcc[1][threadIdx.x]
                  + sAcc[2][threadIdx.x] + sAcc[3][threadIdx.x];
        sum *= mask[za];
        atomicAdd(&out[(size_t)za * 64 + threadIdx.x], sum);
    }
}

extern "C" void kernel_launch(void* const* d_in, const int* in_sizes, int n_in,
                              void* d_out, int out_size, void* d_ws, size_t ws_size,
                              hipStream_t stream) {
    (void)in_sizes; (void)n_in; (void)d_ws; (void)ws_size; (void)out_size;
    const float* feat = (const float*)d_in[0];
    const float* geom = (const float*)d_in[1];
    const float* mask = (const float*)d_in[2];
    const float* W1   = (const float*)d_in[3];
    const float* b1   = (const float*)d_in[4];
    const float* W2   = (const float*)d_in[5];
    const float* b2   = (const float*)d_in[6];
    float* out = (float*)d_out;

    k_prep<<<470, 256, 0, stream>>>(W1, b1, W2, b2, out);   // 390 table + 80 zero
    k_main<<<2 * NA * CW / 4, 256, 0, stream>>>(feat, geom, mask, out);
}

// Round 10
// 91.800 us; speedup vs baseline: 2.1771x; 1.0172x over previous
//
#include <hip/hip_runtime.h>
#include <hip/hip_fp16.h>
#include <math.h>

#define NPATH 1536
#define NSEG  65
#define NB    160
#define NA    160
#define CW    32   // chunks (waves) per (z,a)
#define PPW   5    // pairs per wave = NB/CW

// Piecewise-linear radial-MLP table, fp16-packed: one 16B entry holds a
// lane's 4 slots: {h2(s0,s1), h2(s2,s3), h2(i0,i1), h2(i2,i3)}; R_k(r) =
// r*s_k + i_k (computed in f32). Per-block Wigner/norm constants pre-folded.
// Per segment: 512 entries (8 KB): [0..255] l0 (v*16+u) -> slots {A,B,0,0};
// [256..511] l1 (v*16+u) -> slots {C,D,E,F}.
__device__ float  dg_thr[64];    // per-channel threshold -b1/W1 (inf if W1==0)
__device__ float4 dg_tbl4[NSEG * 512];

static __device__ __forceinline__ __half2 bc_h2(float x) {
    union { float f; __half2 h; } u; u.f = x; return u.h;
}
static __device__ __forceinline__ unsigned short h_us(__half h) {
    union { __half h; unsigned short s; } u; u.h = h; return u.s;
}

// blocks 0..389: table (one thread per (segment,path), direct masked sums —
// activity is a pure rank predicate, rank-sort recomputed per block).
// blocks 390..469: zero d_out.
__global__ __launch_bounds__(256) void k_prep(const float* __restrict__ W1,
                                              const float* __restrict__ b1,
                                              const float* __restrict__ W2,
                                              const float* __restrict__ b2,
                                              float* __restrict__ out) {
    int bid = blockIdx.x, tid = threadIdx.x;
    if (bid >= 390) {
        out[(bid - 390) * 256 + tid] = 0.0f;
        return;
    }
    int tseg = bid / 6, tcol = bid % 6;
    __shared__ float tv[64], mw[64], mb[64];
    if (tid < 64) {
        float w = W1[tid], b = b1[tid];
        tv[tid] = (w != 0.0f) ? (-b / w) : __builtin_inff();
    }
    __syncthreads();
    if (tid < 64) {
        float mine = tv[tid];
        int rank = 0;
        for (int j = 0; j < 64; ++j) {
            float o = tv[j];
            rank += (o < mine || (o == mine && j < tid)) ? 1 : 0;
        }
        float w = W1[tid], b = b1[tid];
        // active at segment s (= #thresholds < r):
        //   w>0: rank < s ; w<0: rank >= s ; w==0: b>0
        bool act = (w > 0.0f) ? (rank < tseg)
                 : (w < 0.0f) ? (rank >= tseg)
                              : (b > 0.0f);
        mw[tid] = act ? w : 0.0f;
        mb[tid] = act ? b : 0.0f;
        if (bid == 0) dg_thr[tid] = mine;
    }
    __syncthreads();

    int p = tcol * 256 + tid;
    int e, k; float scl;
    if (p < 768) {
        int u = (p >> 4) & 15, v = p & 15, vu = v * 16 + u;
        if (p < 256)      { e = vu;       k = 0; scl = 0.17677669529663687f; } // A
        else if (p < 512) { e = vu;       k = 1; scl = 0.6266570686577502f;  } // B
        else              { e = 256 + vu; k = 0; scl = 0.2558286876965162f;  } // C
    } else {
        int m = (p - 768) / 3, kk = (p - 768) % 3;
        int u = m >> 4, v = m & 15, vu = v * 16 + u;
        e = 256 + vu;
        if (kk == 0)      { k = 1; scl = 0.125f;              }  // D
        else if (kk == 1) { k = 2; scl = 0.3133285343288751f; }  // E
        else              { k = 3; scl = 0.7674950309598664f; }  // F
    }

    float A = 0.0f, B = 0.0f;
    #pragma unroll 8
    for (int c = 0; c < 64; ++c) {
        float w2 = W2[c * NPATH + p];   // coalesced across tid; W2 is L2-hot
        A = fmaf(mw[c], w2, A);
        B = fmaf(mb[c], w2, B);
    }
    float sv = scl * A;
    float iv = scl * (B + b2[p]);

    unsigned short* ub = (unsigned short*)dg_tbl4 + ((size_t)tseg * 512 + e) * 8;
    ub[k]     = h_us(__float2half(sv));   // slope slot k  (ushorts 0..3)
    ub[4 + k] = h_us(__float2half(iv));   // icpt  slot k  (ushorts 4..7)
    if (p < 256) {                        // A-thread zeroes the l0 pad slots 2,3
        ((unsigned int*)ub)[1] = 0u;      // s2,s3
        ((unsigned int*)ub)[3] = 0u;      // i2,i3
    }
}

__global__ __launch_bounds__(256, 4) void k_main(const float* __restrict__ feat,
                                                 const float* __restrict__ geom,
                                                 const float* __restrict__ mask,
                                                 float* __restrict__ out) {
    int wv   = threadIdx.x >> 6;
    int lane = threadIdx.x & 63;
    int gw   = blockIdx.x * 4 + wv;     // 4 waves of a block share za
    int chunk = gw & (CW - 1);
    int za    = gw >> 5;                // z*160 + a
    int z     = za / NA;

    __shared__ __align__(16) float sFeat[4][PPW][64]; // slot v = {f1x,f1y,f1z,f0}
    __shared__ float sAcc[4][64];

    // ---- v-split task assignment (dedup: 32 tasks x 2 v-halves) ----
    int h    = lane >> 5;          // which v-half this lane accumulates
    int l32  = lane & 31;
    bool tl0 = l32 < 16;           // task type: l0 (A/B) vs l1 (C/D/E/F)
    int  tu  = l32 & 15;           // task u
    int  e_base = (tl0 ? 0 : 256) + h * 16 + tu;   // entry idx of (v=h, u)
    float zft = tl0 ? 1.4142135623730951f : 2.0f;  // zero-radius norm ratio (task)

    // input staging address (same layout as before)
    int waddr = (lane < 16) ? (lane * 4 + 3)
                            : (((lane - 16) / 3) * 4 + ((lane - 16) % 3));

    float thrv = dg_thr[lane];

    const float is30 = 0.18257418583505536f;  // 1/sqrt(30)
    const float is10 = 0.31622776601683794f;  // 1/sqrt(10)
    const float c1sh = 0.4886025119029199f;
    const float c21 = 1.0925484305920792f, c22 = 0.31539156525252005f, c23 = 0.5462742152960396f;

    // ---- stage all PPW feature rows (wave-private LDS slot, no barrier) ----
    int b0 = chunk * PPW;
    #pragma unroll
    for (int it = 0; it < PPW; ++it) {
        float fv = feat[((size_t)(z * NB + b0 + it)) * 64 + lane];
        sFeat[wv][it][waddr] = fv;
    }

    // ---- precompute geometry/segment for all PPW pairs ----
    float rr[PPW], nxa[PPW], nya[PPW], nza[PPW], zfa[PPW];
    int rowo[PPW];
    #pragma unroll
    for (int it = 0; it < PPW; ++it) {
        const float* g = geom + ((size_t)za * NB + b0 + it) * 3;
        float gx = g[0], gy = g[1], gz = g[2];
        float r = sqrtf(gx * gx + gy * gy + gz * gz);
        bool zr = (r == 0.0f);
        float inv = zr ? 1.0f : (1.0f / r);
        nxa[it] = gx * inv; nya[it] = gy * inv; nza[it] = gz * inv;
        rr[it] = r;
        zfa[it] = zr ? zft : 1.0f;
        unsigned long long bm = __ballot(thrv < r);
        rowo[it] = __popcll(bm) * 512;
    }

    // per-task output accumulators: l0 task -> acc0; l1 task -> acc0/1/2 = s_x/y/z
    float acc0 = 0.0f, acc1 = 0.0f, acc2 = 0.0f;

    // ---- software pipeline: register double-buffer of table entries ----
    float4 tb[2][8];
    {
        const float4* __restrict__ rp0 = dg_tbl4 + rowo[0] + e_base;
        #pragma unroll
        for (int s = 0; s < 8; ++s) tb[0][s] = rp0[s * 32];
    }

    #pragma unroll
    for (int it = 0; it < PPW; ++it) {
        // issue next pair's loads before consuming this pair's buffer
        if (it + 1 < PPW) {
            const float4* __restrict__ rpn = dg_tbl4 + rowo[it + 1] + e_base;
            #pragma unroll
            for (int s = 0; s < 8; ++s) tb[(it + 1) & 1][s] = rpn[s * 32];
        }

        float r = rr[it];
        const float* spL = &sFeat[wv][it][0] + h * 4;   // this half's v features
        float T0 = 0.0f;
        float T1x = 0.0f, T1y = 0.0f, T1z = 0.0f;
        float T2x = 0.0f, T2y = 0.0f, T2z = 0.0f;
        float T3x = 0.0f, T3y = 0.0f, T3z = 0.0f;
        #pragma unroll
        for (int s = 0; s < 8; ++s) {
            float4 t = tb[it & 1][s];   // {s01,s23,i01,i23} fp16-packed
            __half2 hs01 = bc_h2(t.x), hs23 = bc_h2(t.y);
            __half2 hi01 = bc_h2(t.z), hi23 = bc_h2(t.w);
            float R0 = fmaf(r, __low2float(hs01),  __low2float(hi01));
            float R1 = fmaf(r, __high2float(hs01), __high2float(hi01));
            float R2 = fmaf(r, __low2float(hs23),  __low2float(hi23));
            float R3 = fmaf(r, __high2float(hs23), __high2float(hi23));
            float4 fq = *(const float4*)&spL[s * 8];  // {f1x,f1y,f1z,f0} for v=2s+h
            T0  = fmaf(R0, fq.w, T0);
            T1x = fmaf(R1, fq.x, T1x);
            T1y = fmaf(R1, fq.y, T1y);
            T1z = fmaf(R1, fq.z, T1z);
            T2x = fmaf(R2, fq.x, T2x);
            T2y = fmaf(R2, fq.y, T2y);
            T2z = fmaf(R2, fq.z, T2z);
            T3x = fmaf(R3, fq.x, T3x);
            T3y = fmaf(R3, fq.y, T3y);
            T3z = fmaf(R3, fq.z, T3z);
        }

        // ---- per-task contraction (no cross-lane traffic) ----
        float nx = nxa[it], ny = nya[it], nz = nza[it];
        // real SH (e3nn convention; l=1 order y,z,x)
        float Y1_0 = c1sh * ny, Y1_1 = c1sh * nz, Y1_2 = c1sh * nx;
        float Y2_0 = c21 * nx * ny;
        float Y2_1 = c21 * ny * nz;
        float Y2_2 = c22 * fmaf(3.0f, nz * nz, -1.0f);
        float Y2_3 = c21 * nx * nz;
        float Y2_4 = c23 * (nx * nx - ny * ny);
        float za_ = is10 * Y2_0, zb_ = is10 * Y2_1, zc_ = is10 * Y2_3;
        float zd_ = is30 * Y2_2, ze_ = is10 * Y2_4;

        // l0 task: s = T0 + Y1.T1   (slots A,B; T2/T3 are zero)
        float sl0 = T0;
        sl0 = fmaf(Y1_0, T1x, sl0);
        sl0 = fmaf(Y1_1, T1y, sl0);
        sl0 = fmaf(Y1_2, T1z, sl0);

        // l1 task, output i: s_i = Y1_i*T0 + T1_i + cross_i(T2) + Z_i(T3)
        float sx = fmaf(Y1_0, T0, T1x);
        sx = fmaf(Y1_2, T2y, sx); sx = fmaf(-Y1_1, T2z, sx);
        sx = fmaf(-(zd_ + ze_), T3x, sx); sx = fmaf(zb_, T3y, sx); sx = fmaf(za_, T3z, sx);

        float sy = fmaf(Y1_1, T0, T1y);
        sy = fmaf(-Y1_2, T2x, sy); sy = fmaf(Y1_0, T2z, sy);
        sy = fmaf(zb_, T3x, sy); sy = fmaf(2.0f * zd_, T3y, sy); sy = fmaf(zc_, T3z, sy);

        float sz = fmaf(Y1_2, T0, T1z);
        sz = fmaf(Y1_1, T2x, sz); sz = fmaf(-Y1_0, T2y, sz);
        sz = fmaf(za_, T3x, sz); sz = fmaf(zc_, T3y, sz); sz = fmaf(ze_ - zd_, T3z, sz);

        float s0 = tl0 ? sl0 : sx;
        float zf = zfa[it];
        acc0 = fmaf(s0, zf, acc0);
        acc1 = fmaf(sy, zf, acc1);
        acc2 = fmaf(sz, zf, acc2);
    }

    // ---- combine the two v-halves: 3 shuffles total ----
    acc0 += __shfl_xor(acc0, 32);
    acc1 += __shfl_xor(acc1, 32);
    acc2 += __shfl_xor(acc2, 32);

    if (lane < 32) {
        if (tl0) {
            sAcc[wv][tu] = acc0;
        } else {
            int ob = 16 + tu * 3;
            sAcc[wv][ob]     = acc0;
            sAcc[wv][ob + 1] = acc1;
            sAcc[wv][ob + 2] = acc2;
        }
    }
    __syncthreads();
    if (threadIdx.x < 64) {
        float sum = sAcc[0][threadIdx.x] + sAcc[1][threadIdx.x]
                  + sAcc[2][threadIdx.x] + sAcc[3][threadIdx.x];
        sum *= mask[za];
        atomicAdd(&out[(size_t)za * 64 + threadIdx.x], sum);
    }
}

extern "C" void kernel_launch(void* const* d_in, const int* in_sizes, int n_in,
                              void* d_out, int out_size, void* d_ws, size_t ws_size,
                              hipStream_t stream) {
    (void)in_sizes; (void)n_in; (void)d_ws; (void)ws_size; (void)out_size;
    const float* feat = (const float*)d_in[0];
    const float* geom = (const float*)d_in[1];
    const float* mask = (const float*)d_in[2];
    const float* W1   = (const float*)d_in[3];
    const float* b1   = (const float*)d_in[4];
    const float* W2   = (const float*)d_in[5];
    const float* b2   = (const float*)d_in[6];
    float* out = (float*)d_out;

    k_prep<<<470, 256, 0, stream>>>(W1, b1, W2, b2, out);   // 390 table + 80 zero
    k_main<<<2 * NA * CW / 4, 256, 0, stream>>>(feat, geom, mask, out);
}